// Round 10
// baseline (23.955 us; speedup 1.0000x reference)
//
#include <hip/hip_runtime.h>

#define BB 16
#define NN 65536
#define KK 64
#define TPB 256
#define EPB 2048                  // 8 elems/thread: two half-chunks of 1024
#define NBLK ((BB * NN) / EPB)    // 512 blocks = 2/CU

__device__ __forceinline__ float readlane_f(float v, int lane) {
    return __uint_as_float((unsigned)__builtin_amdgcn_readlane((int)__float_as_uint(v), lane));
}

__device__ __forceinline__ float4 load4(const float* p) {
    float4 v;
    __builtin_memcpy(&v, p, 16);   // global_load_dwordx4, align-4 ok
    return v;
}

__global__ __launch_bounds__(TPB) void frac_deriv_kernel(
    const float* __restrict__ x,
    const float* __restrict__ loc,
    const float* __restrict__ scale,
    const float* __restrict__ eps,
    const int* __restrict__ lags,
    float* __restrict__ out)
{
    __shared__ int   js_raw[KK];
    __shared__ float ws_raw[KK];
    __shared__ int   js[KK];
    __shared__ float ws[KK];

    const int tid  = threadIdx.x;
    const int lane = tid & 63;

    // Bijective XCD swizzle: 512 blocks -> 64/XCD = 2 rows; heavy-first in chunk.
    const int bid = blockIdx.x;
    const int swz = (bid & 7) * (NBLK / 8) + (bid >> 3);
    const int b   = swz >> 5;            // row [0,16)  (32 blocks/row)
    const int q   = 31 - (swz & 31);     // heavy-first
    const int T   = q * EPB;

    const float* __restrict__ xr = x + (size_t)b * NN;
    const int e0 = T + 4 * tid;          // low half  [T,     T+1024)
    const int e1 = e0 + 1024;            // high half [T+1024,T+2048)
    const float4 xt0 = load4(xr + e0);   // early issue
    const float4 xt1 = load4(xr + e1);

    // --- Prologue: wave 0 computes f64 weights, rank-sorts lags (measured free).
    if (tid < KK) {
        double s  = (double)scale[0];
        double sp = (s > 20.0) ? s : log1p(exp(s));
        double a  = (double)loc[0] + sp * (double)eps[0];
        a = fmin(fmax(a, 0.01), 0.99);
        double c = a * exp(-lgamma(1.0 - a)) * ((double)(NN - 1) / (double)KK);
        int j = lags[tid];
        j = (j < 1) ? 1 : ((j > NN - 1) ? NN - 1 : j);
        js_raw[tid] = j;
        ws_raw[tid] = (float)(c * exp(-(a + 1.0) * log((double)j)));
    }
    __syncthreads();
    if (tid < KK) {
        const int j = js_raw[tid];
        int rank = 0;
        for (int k = 0; k < KK; ++k) {
            const int jk = js_raw[k];
            rank += (int)((jk < j) || (jk == j && k < tid));
        }
        js[rank] = j;
        ws[rank] = ws_raw[tid];
    }
    __syncthreads();

    const int   jv = js[lane];
    const float wv = ws[lane];
    const int cf = __popcll(__ballot(jv <= T));             // fully-valid prefix
    const int cp = __popcll(__ballot(jv <= T + (EPB - 1))); // incl. straddle
    const int cf8 = cf & ~7;

    double a0 = 0.0, a1 = 0.0, a2 = 0.0, a3 = 0.0;
    double a4 = 0.0, a5 = 0.0, a6 = 0.0, a7 = 0.0;

    // --- Sorted-lag order: consecutive windows overlap by EPB-dj (~50%), and the
    //     overlap is L1-resident (8KB window, 2 blocks/CU -> 32KB WS = L1 size).
    for (int mo = 0; mo < cf8; mo += 8) {
        float4 u[8], v[8];
#pragma unroll
        for (int mi = 0; mi < 8; ++mi) {
            const int jj = __builtin_amdgcn_readlane(jv, mo + mi);
            const float* bp = xr + (e0 - jj);
            u[mi] = load4(bp);            // low half gather
            v[mi] = load4(bp + 1024);     // high half gather
        }
        float g0 = 0.f, g1 = 0.f, g2 = 0.f, g3 = 0.f;
        float g4 = 0.f, g5 = 0.f, g6 = 0.f, g7 = 0.f;
#pragma unroll
        for (int mi = 0; mi < 8; ++mi) {
            const float wm = readlane_f(wv, mo + mi);
            g0 = fmaf(xt0.x - u[mi].x, wm, g0);
            g1 = fmaf(xt0.y - u[mi].y, wm, g1);
            g2 = fmaf(xt0.z - u[mi].z, wm, g2);
            g3 = fmaf(xt0.w - u[mi].w, wm, g3);
            g4 = fmaf(xt1.x - v[mi].x, wm, g4);
            g5 = fmaf(xt1.y - v[mi].y, wm, g5);
            g6 = fmaf(xt1.z - v[mi].z, wm, g6);
            g7 = fmaf(xt1.w - v[mi].w, wm, g7);
        }
        a0 += (double)g0; a1 += (double)g1; a2 += (double)g2; a3 += (double)g3;
        a4 += (double)g4; a5 += (double)g5; a6 += (double)g6; a7 += (double)g7;
    }

    // --- Tail: remaining valid + straddle lags, per-element masked clamp.
    for (int m = cf8; m < cp; ++m) {
        const int   jj = __builtin_amdgcn_readlane(jv, m);
        const float wm = readlane_f(wv, m);
        const int d0 = e0 - jj;
        const int d1 = e1 - jj;
        const float p0 = xr[(d0     < 0) ? 0 : d0];
        const float p1 = xr[(d0 + 1 < 0) ? 0 : d0 + 1];
        const float p2 = xr[(d0 + 2 < 0) ? 0 : d0 + 2];
        const float p3 = xr[(d0 + 3 < 0) ? 0 : d0 + 3];
        const float p4 = xr[(d1     < 0) ? 0 : d1];
        const float p5 = xr[(d1 + 1 < 0) ? 0 : d1 + 1];
        const float p6 = xr[(d1 + 2 < 0) ? 0 : d1 + 2];
        const float p7 = xr[(d1 + 3 < 0) ? 0 : d1 + 3];
        a0 += (d0     >= 0) ? (double)((xt0.x - p0) * wm) : 0.0;
        a1 += (d0 + 1 >= 0) ? (double)((xt0.y - p1) * wm) : 0.0;
        a2 += (d0 + 2 >= 0) ? (double)((xt0.z - p2) * wm) : 0.0;
        a3 += (d0 + 3 >= 0) ? (double)((xt0.w - p3) * wm) : 0.0;
        a4 += (d1     >= 0) ? (double)((xt1.x - p4) * wm) : 0.0;
        a5 += (d1 + 1 >= 0) ? (double)((xt1.y - p5) * wm) : 0.0;
        a6 += (d1 + 2 >= 0) ? (double)((xt1.z - p6) * wm) : 0.0;
        a7 += (d1 + 3 >= 0) ? (double)((xt1.w - p7) * wm) : 0.0;
    }

    float* __restrict__ orow = out + (size_t)b * NN;
    float4 r0 = make_float4((float)a0, (float)a1, (float)a2, (float)a3);
    float4 r1 = make_float4((float)a4, (float)a5, (float)a6, (float)a7);
    __builtin_memcpy(orow + e0, &r0, 16);
    __builtin_memcpy(orow + e1, &r1, 16);
}

extern "C" void kernel_launch(void* const* d_in, const int* in_sizes, int n_in,
                              void* d_out, int out_size, void* d_ws, size_t ws_size,
                              hipStream_t stream) {
    const float* x     = (const float*)d_in[0];
    const float* loc   = (const float*)d_in[1];
    const float* scale = (const float*)d_in[2];
    const float* eps   = (const float*)d_in[3];
    const int*   lags  = (const int*)d_in[4];
    float* out = (float*)d_out;

    frac_deriv_kernel<<<NBLK, TPB, 0, stream>>>(x, loc, scale, eps, lags, out);
}